// Round 3
// baseline (273.703 us; speedup 1.0000x reference)
//
#include <hip/hip_runtime.h>
#include <hip/hip_bf16.h>

#define Bn   8
#define Cn   64
#define Nn   40962
#define Kn   7
#define OUTn 64
// flattened K dim = Kn*Cn = 448 = 14 chunks of 32

typedef __bf16 bf16x8 __attribute__((ext_vector_type(8)));
typedef float  f32x4  __attribute__((ext_vector_type(4)));

// ---------------------------------------------------------------------------
// Convert W [64,448] f32 -> bf16 once per call.
// ---------------------------------------------------------------------------
__global__ __launch_bounds__(256) void convw_kernel(
    const float* __restrict__ W, __bf16* __restrict__ Wb)
{
    int i = blockIdx.x * 256 + threadIdx.x;
    if (i < OUTn * Kn * Cn) Wb[i] = (__bf16)W[i];
}

// ---------------------------------------------------------------------------
// Pass 1: transpose+convert a chunk of batches x [B, C, N] f32 -> xT [nb, N, C]
// bf16, so each gathered neighborhood row is 128 B contiguous.
// ---------------------------------------------------------------------------
__global__ __launch_bounds__(256) void transpose_kernel(
    const float* __restrict__ x, __bf16* __restrict__ xT, int b0)
{
    __shared__ __bf16 tile[64][65];
    const int n0 = blockIdx.x * 64;
    const int bl = blockIdx.y;          // local batch in chunk
    const int b  = b0 + bl;             // global batch
    const int tx = threadIdx.x & 63;
    const int tg = threadIdx.x >> 6;

    const size_t xb = (size_t)b * Cn * Nn;
    const int n = n0 + tx;
    if (n < Nn) {
#pragma unroll
        for (int i = 0; i < 16; ++i) {
            int c = tg * 16 + i;
            tile[c][tx] = (__bf16)x[xb + (size_t)c * Nn + n];
        }
    }
    __syncthreads();
#pragma unroll
    for (int i = 0; i < 16; ++i) {
        int no = tg * 16 + i;
        if (n0 + no < Nn)
            xT[((size_t)bl * Nn + n0 + no) * Cn + tx] = tile[tx][no];
    }
}

// ---------------------------------------------------------------------------
// Pass 2: gather-GEMM via MFMA 16x16x32 bf16, f32 accumulate + f32 store.
//   A = Wb : A[m=o][k]       lane: o = s*16 + (lane&15), 16B contiguous k
//   B = xT : B[k][n=vertex]  lane: v = t*16 + (lane&15), 16B contiguous at
//                            xT[bl, idx(v,kn), (kc&1)*32 + quad*8]
//   D: col = lane&15 -> vertex, row = quad*4 + reg -> o
// Wave tile: 64 vertices x 64 outputs. Block: 4 waves = 256 vertices.
// ---------------------------------------------------------------------------
__global__ __launch_bounds__(256) void gconv_kernel(
    const __bf16* __restrict__ xT,    // [nb, N, C] bf16
    const int*    __restrict__ nbr,   // [N*7] int32
    const __bf16* __restrict__ Wb,    // [64, 448] bf16
    const float*  __restrict__ bias,  // [64] f32
    float*        __restrict__ out,   // [B, 64, N] f32
    int b0)
{
    const int w    = threadIdx.x >> 6;
    const int l    = threadIdx.x & 63;
    const int col  = l & 15;
    const int quad = l >> 4;
    const int bl   = blockIdx.y;
    const int b    = b0 + bl;
    const int nbase = blockIdx.x * 256 + w * 64;

    // Neighbor indices for this wave's 64 vertices; clamp for safety.
    int idxs[4][7];
#pragma unroll
    for (int t = 0; t < 4; ++t) {
        int v = nbase + t * 16 + col;
        bool ok = v < Nn;
        int vb = ok ? v * 7 : 0;
#pragma unroll
        for (int kn = 0; kn < 7; ++kn) {
            int id = ok ? nbr[vb + kn] : 0;
            id = id < 0 ? 0 : (id >= Nn ? Nn - 1 : id);
            idxs[t][kn] = id;
        }
    }

    f32x4 acc[4][4];
#pragma unroll
    for (int s = 0; s < 4; ++s)
#pragma unroll
        for (int t = 0; t < 4; ++t)
            acc[s][t] = (f32x4){0.f, 0.f, 0.f, 0.f};

    const __bf16* xb = xT + (size_t)bl * Nn * Cn;

#pragma unroll
    for (int kc = 0; kc < 14; ++kc) {
        const int kn = kc >> 1;
        const int c0 = (kc & 1) * 32 + quad * 8;

        bf16x8 afrag[4];
#pragma unroll
        for (int s = 0; s < 4; ++s)
            afrag[s] = *(const bf16x8*)(Wb + (size_t)(s * 16 + col) * (Kn * Cn)
                                           + kc * 32 + quad * 8);

        bf16x8 bfrag[4];
#pragma unroll
        for (int t = 0; t < 4; ++t)
            bfrag[t] = *(const bf16x8*)(xb + (size_t)idxs[t][kn] * Cn + c0);

#pragma unroll
        for (int s = 0; s < 4; ++s)
#pragma unroll
            for (int t = 0; t < 4; ++t)
                acc[s][t] = __builtin_amdgcn_mfma_f32_16x16x32_bf16(
                    afrag[s], bfrag[t], acc[s][t], 0, 0, 0);
    }

#pragma unroll
    for (int s = 0; s < 4; ++s) {
#pragma unroll
        for (int r = 0; r < 4; ++r) {
            const int o = s * 16 + quad * 4 + r;
            const float bv = bias[o];
#pragma unroll
            for (int t = 0; t < 4; ++t) {
                const int n = nbase + t * 16 + col;
                if (n < Nn)
                    out[((size_t)b * OUTn + o) * Nn + n] = acc[s][t][r] + bv;
            }
        }
    }
}

// ---------------------------------------------------------------------------
// Fallback: no workspace needed. Pure f32. 4 vertices per block; LDS-staged
// gather, scalar dot products. Slow but correct.
// ---------------------------------------------------------------------------
__global__ __launch_bounds__(256) void naive_kernel(
    const float* __restrict__ x,      // [B, C, N]
    const int*   __restrict__ nbr,
    const float* __restrict__ W,
    const float* __restrict__ bias,
    float*       __restrict__ out)
{
    __shared__ float xs[4][Kn * Cn];
    const int v = threadIdx.x >> 6;
    const int o = threadIdx.x & 63;
    const int b = blockIdx.y;
    const int n = blockIdx.x * 4 + v;
    const bool ok = n < Nn;
    const int nn = ok ? n : 0;

#pragma unroll
    for (int k = 0; k < Kn; ++k) {
        int id = nbr[nn * Kn + k];
        id = id < 0 ? 0 : (id >= Nn ? Nn - 1 : id);
        xs[v][k * Cn + o] = x[((size_t)b * Cn + o) * Nn + id];
    }
    __syncthreads();

    float acc = bias[o];
    for (int j = 0; j < Kn * Cn; ++j)
        acc += W[o * (Kn * Cn) + j] * xs[v][j];

    if (ok)
        out[((size_t)b * OUTn + o) * Nn + n] = acc;
}

extern "C" void kernel_launch(void* const* d_in, const int* in_sizes, int n_in,
                              void* d_out, int out_size, void* d_ws, size_t ws_size,
                              hipStream_t stream)
{
    const float* x    = (const float*)d_in[0];
    const int*   nbr  = (const int*)d_in[1];
    const float* W    = (const float*)d_in[2];
    const float* bias = (const float*)d_in[3];
    float*       out  = (float*)d_out;

    const size_t w_bytes     = (size_t)OUTn * Kn * Cn * sizeof(__bf16); // 57344
    const size_t batch_bytes = (size_t)Nn * Cn * sizeof(__bf16);        // 5.24 MB
    int nb = 0;
    if (ws_size > w_bytes)
        nb = (int)((ws_size - w_bytes) / batch_bytes);
    if (nb > Bn) nb = Bn;

    if (nb >= 1) {
        __bf16* Wb = (__bf16*)d_ws;
        __bf16* xT = (__bf16*)((char*)d_ws + w_bytes);

        convw_kernel<<<(OUTn * Kn * Cn + 255) / 256, 256, 0, stream>>>(W, Wb);

        for (int b0 = 0; b0 < Bn; b0 += nb) {
            int cur = (Bn - b0) < nb ? (Bn - b0) : nb;
            dim3 tgrid((Nn + 63) / 64, cur);
            transpose_kernel<<<tgrid, 256, 0, stream>>>(x, xT, b0);
            dim3 ggrid((Nn + 255) / 256, cur);
            gconv_kernel<<<ggrid, 256, 0, stream>>>(xT, nbr, Wb, bias, out, b0);
        }
    } else {
        dim3 ngrid((Nn + 3) / 4, Bn);
        naive_kernel<<<ngrid, 256, 0, stream>>>(x, nbr, W, bias, out);
    }
}

// Round 4
// 264.885 us; speedup vs baseline: 1.0333x; 1.0333x over previous
//
#include <hip/hip_runtime.h>
#include <hip/hip_bf16.h>

#define Bn   8
#define Cn   64
#define Nn   40962
#define Kn   7
#define OUTn 64
// flattened K dim = Kn*Cn = 448 = 14 chunks of 32

typedef __bf16 bf16x8 __attribute__((ext_vector_type(8)));
typedef __bf16 bf16x4 __attribute__((ext_vector_type(4)));
typedef float  f32x4  __attribute__((ext_vector_type(4)));

// ---------------------------------------------------------------------------
// Convert W [64,448] f32 -> bf16 once per call.
// ---------------------------------------------------------------------------
__global__ __launch_bounds__(256) void convw_kernel(
    const float* __restrict__ W, __bf16* __restrict__ Wb)
{
    int i = blockIdx.x * 256 + threadIdx.x;
    if (i < OUTn * Kn * Cn) Wb[i] = (__bf16)W[i];
}

// ---------------------------------------------------------------------------
// Pass 1: transpose+convert x [B, C, N] f32 -> xT [nb, N, C] bf16.
// n-major LDS tile so the output side is vectorized (ds_read_b64 + 8-B
// global stores). Input side: 16 coalesced scalar f32 loads per thread
// (256 B per wave-instruction).
// ---------------------------------------------------------------------------
__global__ __launch_bounds__(256) void transpose_kernel(
    const float* __restrict__ x, __bf16* __restrict__ xT, int b0)
{
    __shared__ __bf16 tile[64][68];   // [n][c]; pad 68 keeps b64 reads 8B-aligned
    const int tid  = threadIdx.x;
    const int lane = tid & 63;
    const int w    = tid >> 6;
    const int n0   = blockIdx.x * 64;
    const int bl   = blockIdx.y;       // local batch in chunk
    const int b    = b0 + bl;

    const size_t xb = (size_t)b * Cn * Nn;
    const int n = n0 + lane;
    if (n < Nn) {
#pragma unroll
        for (int i = 0; i < 16; ++i) {
            int c = w * 16 + i;
            tile[lane][c] = (__bf16)x[xb + (size_t)c * Nn + n];
        }
    }
    __syncthreads();

    // Output: 4 iterations; each wave-instruction covers 4 rows x 64 c.
#pragma unroll
    for (int j = 0; j < 4; ++j) {
        int row = j * 16 + (tid >> 4);
        int c4  = (tid & 15) * 4;
        if (n0 + row < Nn) {
            bf16x4 v = *(const bf16x4*)&tile[row][c4];
            *(bf16x4*)(xT + ((size_t)bl * Nn + n0 + row) * Cn + c4) = v;
        }
    }
}

// ---------------------------------------------------------------------------
// Pass 2: gather-GEMM via MFMA 16x16x32 bf16, f32 accumulate + f32 store.
//   A = Wb : A[m=o][k]       lane: o = s*16 + (lane&15), 16B contiguous k
//   B = xT : B[k][n=vertex]  lane: v = t*16 + (lane&15), 16B contiguous at
//                            xT[bl, idx(v,kn), (kc&1)*32 + quad*8]
//   D: col = lane&15 -> vertex, row = quad*4 + reg -> o
// Wave tile: 64 vertices x 64 outputs. Block: 4 waves = 256 vertices.
// Grid is flattened; bl = blockIdx.x % curB pins each batch to one XCD when
// curB == 8 (consecutive blocks round-robin XCDs), shrinking each XCD's L2
// gather working set from 42 MB to one 5.25 MB batch slice.
// ---------------------------------------------------------------------------
__global__ __launch_bounds__(256) void gconv_kernel(
    const __bf16* __restrict__ xT,    // [nb, N, C] bf16
    const int*    __restrict__ nbr,   // [N*7] int32
    const __bf16* __restrict__ Wb,    // [64, 448] bf16
    const float*  __restrict__ bias,  // [64] f32
    float*        __restrict__ out,   // [B, 64, N] f32
    int b0, int curB)
{
    const int bl    = blockIdx.x % curB;
    const int vtile = blockIdx.x / curB;
    const int w     = threadIdx.x >> 6;
    const int l     = threadIdx.x & 63;
    const int col   = l & 15;
    const int quad  = l >> 4;
    const int b     = b0 + bl;
    const int nbase = vtile * 256 + w * 64;

    // Neighbor indices for this wave's 64 vertices; clamp for safety.
    int idxs[4][7];
#pragma unroll
    for (int t = 0; t < 4; ++t) {
        int v = nbase + t * 16 + col;
        bool ok = v < Nn;
        int vb = ok ? v * 7 : 0;
#pragma unroll
        for (int kn = 0; kn < 7; ++kn) {
            int id = ok ? nbr[vb + kn] : 0;
            id = id < 0 ? 0 : (id >= Nn ? Nn - 1 : id);
            idxs[t][kn] = id;
        }
    }

    f32x4 acc[4][4];
#pragma unroll
    for (int s = 0; s < 4; ++s)
#pragma unroll
        for (int t = 0; t < 4; ++t)
            acc[s][t] = (f32x4){0.f, 0.f, 0.f, 0.f};

    const __bf16* xb = xT + (size_t)bl * Nn * Cn;

#pragma unroll
    for (int kc = 0; kc < 14; ++kc) {
        const int kn = kc >> 1;
        const int c0 = (kc & 1) * 32 + quad * 8;

        bf16x8 afrag[4];
#pragma unroll
        for (int s = 0; s < 4; ++s)
            afrag[s] = *(const bf16x8*)(Wb + (size_t)(s * 16 + col) * (Kn * Cn)
                                           + kc * 32 + quad * 8);

        bf16x8 bfrag[4];
#pragma unroll
        for (int t = 0; t < 4; ++t)
            bfrag[t] = *(const bf16x8*)(xb + (size_t)idxs[t][kn] * Cn + c0);

#pragma unroll
        for (int s = 0; s < 4; ++s)
#pragma unroll
            for (int t = 0; t < 4; ++t)
                acc[s][t] = __builtin_amdgcn_mfma_f32_16x16x32_bf16(
                    afrag[s], bfrag[t], acc[s][t], 0, 0, 0);
    }

#pragma unroll
    for (int s = 0; s < 4; ++s) {
#pragma unroll
        for (int r = 0; r < 4; ++r) {
            const int o = s * 16 + quad * 4 + r;
            const float bv = bias[o];
#pragma unroll
            for (int t = 0; t < 4; ++t) {
                const int n = nbase + t * 16 + col;
                if (n < Nn)
                    out[((size_t)b * OUTn + o) * Nn + n] = acc[s][t][r] + bv;
            }
        }
    }
}

// ---------------------------------------------------------------------------
// Fallback: no workspace needed. Pure f32. Slow but correct.
// ---------------------------------------------------------------------------
__global__ __launch_bounds__(256) void naive_kernel(
    const float* __restrict__ x,      // [B, C, N]
    const int*   __restrict__ nbr,
    const float* __restrict__ W,
    const float* __restrict__ bias,
    float*       __restrict__ out)
{
    __shared__ float xs[4][Kn * Cn];
    const int v = threadIdx.x >> 6;
    const int o = threadIdx.x & 63;
    const int b = blockIdx.y;
    const int n = blockIdx.x * 4 + v;
    const bool ok = n < Nn;
    const int nn = ok ? n : 0;

#pragma unroll
    for (int k = 0; k < Kn; ++k) {
        int id = nbr[nn * Kn + k];
        id = id < 0 ? 0 : (id >= Nn ? Nn - 1 : id);
        xs[v][k * Cn + o] = x[((size_t)b * Cn + o) * Nn + id];
    }
    __syncthreads();

    float acc = bias[o];
    for (int j = 0; j < Kn * Cn; ++j)
        acc += W[o * (Kn * Cn) + j] * xs[v][j];

    if (ok)
        out[((size_t)b * OUTn + o) * Nn + n] = acc;
}

extern "C" void kernel_launch(void* const* d_in, const int* in_sizes, int n_in,
                              void* d_out, int out_size, void* d_ws, size_t ws_size,
                              hipStream_t stream)
{
    const float* x    = (const float*)d_in[0];
    const int*   nbr  = (const int*)d_in[1];
    const float* W    = (const float*)d_in[2];
    const float* bias = (const float*)d_in[3];
    float*       out  = (float*)d_out;

    const size_t w_bytes     = (size_t)OUTn * Kn * Cn * sizeof(__bf16); // 57344
    const size_t batch_bytes = (size_t)Nn * Cn * sizeof(__bf16);        // 5.24 MB
    int nb = 0;
    if (ws_size > w_bytes)
        nb = (int)((ws_size - w_bytes) / batch_bytes);
    if (nb > Bn) nb = Bn;

    if (nb >= 1) {
        __bf16* Wb = (__bf16*)d_ws;
        __bf16* xT = (__bf16*)((char*)d_ws + w_bytes);

        convw_kernel<<<(OUTn * Kn * Cn + 255) / 256, 256, 0, stream>>>(W, Wb);

        const int vtiles = (Nn + 255) / 256;   // 161
        for (int b0 = 0; b0 < Bn; b0 += nb) {
            int cur = (Bn - b0) < nb ? (Bn - b0) : nb;
            dim3 tgrid((Nn + 63) / 64, cur);
            transpose_kernel<<<tgrid, 256, 0, stream>>>(x, xT, b0);
            gconv_kernel<<<vtiles * cur, 256, 0, stream>>>(xT, nbr, Wb, bias, out, b0, cur);
        }
    } else {
        dim3 ngrid((Nn + 3) / 4, Bn);
        naive_kernel<<<ngrid, 256, 0, stream>>>(x, nbr, W, bias, out);
    }
}